// Round 11
// baseline (2397.208 us; speedup 1.0000x reference)
//
#include <hip/hip_runtime.h>
#include <stdint.h>

// CharRNN MI355X — r8 geometry (16 rows x 64 cols, 160KB LDS) + flag-based
// wave-granular exchange (no counter barrier, logits overlapped).
// r10 = r9 with the s_sleep compile fix (builtin requires CONSTANT operand;
// backoff now branches to three constant call sites).
// Structure (r9 theory under test):
//   - release = __syncthreads (all-wave vmcnt(0) drain, r0-proven) + ONE
//     per-producer flag store (own 128B line; r4-proven protocol). No
//     serialized atomicAdds, no tid0-poll RTT.
//   - wave w restages cols 256w..+255 <- exactly producers 4w..4w+3:
//     wave-local wait on 4 flags (lanes 0..3 poll, 1 lane per line,
//     exponential backoff), then loads; only the existing LDS __syncthreads
//     joins waves.
//   - logits window tsel = t-17+gj (<= t-2; visibility: step t-1's restage
//     waits establish all 16 flags >= t, + syncthreads HB), computed BETWEEN
//     restage-load issue and LDS write -> overlaps the restage MALL RTT.
//     Final window (tsel=496+gj) drained post-loop after all-16 >= 512.
//   Kept verified: ftanh, 4-chain accs, packed col-pair publish, wof layout,
//   XOR-swizzled h_lds, W_hh 1024x64 LDS staging.
// d_ws: proj f32 @0 (256KB) | flags @262144 (32KB: 16grp x 16prod x 128B)
//       | wof @524288 (128KB) | ring bf16 @1MB (16MB)

#define BATCH 256
#define SEQ   512
#define HID   1024
#define VOC   64
#define EMB   256
#define FINAL_OFF (BATCH * SEQ * VOC)   // 8388608
#define RING_SLOTS 32
#define BH (BATCH * HID)

typedef __attribute__((ext_vector_type(8))) short short8;
typedef __attribute__((ext_vector_type(4))) float f32x4;
typedef unsigned long long u64;

__device__ inline unsigned short f2bf(float f) {
  union { float f; unsigned u; } v; v.f = f;
  unsigned u = v.u;
  return (unsigned short)((u + 0x7FFFu + ((u >> 16) & 1u)) >> 16);  // RNE
}

// branch-free tanh: 1 - 2/(e^{2x}+1). Verified r7/r8 (absmax unchanged).
__device__ __forceinline__ float ftanh(float v) {
  float e = __expf(2.0f * v);
  return fmaf(-2.0f, __builtin_amdgcn_rcpf(e + 1.0f), 1.0f);
}

// backoff sleep — s_sleep operand must be a compile-time constant.
__device__ __forceinline__ void backoff(int g) {
  if (g < 64)        __builtin_amdgcn_s_sleep(1);
  else if (g < 1024) __builtin_amdgcn_s_sleep(8);
  else               __builtin_amdgcn_s_sleep(32);
}

// ---- agent-scope (MALL-point) ops — the PROVEN coherence class -------------
__device__ inline u64 cload64(const unsigned short* p) {
  return __hip_atomic_load((const u64*)p, __ATOMIC_RELAXED,
                           __HIP_MEMORY_SCOPE_AGENT);
}
__device__ inline void cstore32(unsigned short* p, unsigned v) {
  __hip_atomic_store((unsigned*)p, v, __ATOMIC_RELAXED,
                     __HIP_MEMORY_SCOPE_AGENT);
}
__device__ inline unsigned fload(const unsigned* p) {
  return __hip_atomic_load(p, __ATOMIC_RELAXED, __HIP_MEMORY_SCOPE_AGENT);
}
__device__ inline void fstore(unsigned* p, unsigned v) {
  __hip_atomic_store(p, v, __ATOMIC_RELAXED, __HIP_MEMORY_SCOPE_AGENT);
}

// ---------------- K1: projection table -------------------------------------
__global__ __launch_bounds__(256) void k_prep(const float* __restrict__ emb,
                                              const float* __restrict__ Wih,
                                              const float* __restrict__ bh,
                                              float* __restrict__ proj) {
  __shared__ float es[EMB];
  const int v = blockIdx.x >> 2;        // 0..63
  const int p = blockIdx.x & 3;         // h-quarter
  const int tid = threadIdx.x;
  es[tid] = emb[v * EMB + tid];
  __syncthreads();
  const int h = p * 256 + tid;
  float acc = bh[h];
  for (int e = 0; e < EMB; ++e) acc += es[e] * Wih[e * HID + h];
  proj[v * HID + h] = acc;
}

// ---------------- K1b: W_ho bf16 fragment table (r6/r7/r8-proven) -----------
// entry e = ((kb*4+q)*4+vt)*16 + l15 ; elems j: Who[(kb*32+q*8+j)*VOC+vt*16+l15]
__global__ __launch_bounds__(256) void k_prep2(const float* __restrict__ Who,
                                               unsigned short* __restrict__ wof) {
  const int e = blockIdx.x * 256 + threadIdx.x;   // 0..8191
  const int l15 = e & 15, vt = (e >> 4) & 3, qq = (e >> 6) & 3, kb = e >> 8;
  #pragma unroll
  for (int j = 0; j < 8; ++j)
    wof[e * 8 + j] = f2bf(Who[(kb * 32 + qq * 8 + j) * VOC + vt * 16 + l15]);
}

// ---------------- K2: persistent recurrence + inline logits ----------------
// LDS: w_lds 131072 (1024x64 bf16 B-frags) | h_lds 32768 (16 x 2048B, XOR swz)
__global__ __launch_bounds__(256, 1) void k_rnn(
    const int* __restrict__ x, const float* __restrict__ Whh,
    const float* __restrict__ proj, const unsigned short* __restrict__ wof,
    const float* __restrict__ bo, unsigned short* __restrict__ ring,
    float* __restrict__ out, float* __restrict__ final_out,
    unsigned int* __restrict__ flags) {
  extern __shared__ char smem[];
  unsigned short* w_lds = (unsigned short*)smem;            // 131072
  char*           h_lds = smem + 131072;                    // 32768

  const int tid = threadIdx.x, bid = blockIdx.x;
  const int gi = bid & 15, gj = bid >> 4;   // group (16 rows) / col-slice (64)
  const int row0 = gi * 16;
  const int lane = tid & 63, wv = tid >> 6;                 // wv = nt slice
  const int l15 = lane & 15, q = lane >> 4;

  // W_hh column slice (1024 x 64) -> LDS bf16 B-fragment order (once).
  for (int it = 0; it < 256; ++it) {
    int u = it * 256 + tid;               // 0..65535
    int k = u >> 6, n = u & 63;           // coalesced over n
    int kb = k >> 5, qq = (k >> 3) & 3, j8 = k & 7;
    w_lds[(size_t)kb * 2048 + qq * 512 + n * 8 + j8] =
        f2bf(Whh[k * HID + gj * 64 + n]);
  }
  __syncthreads();

  // per-producer flags: flags[(gi*16 + gj)*32], 128B lines. r4-proven class.
  unsigned* flagg  = flags + gi * 16 * 32;
  unsigned* myflag = flagg + gj * 32;
  // wave w's restage producers are 4w..4w+3 (cols 256w..+255); lane<4 polls.
  const unsigned* wflag = flagg + (4 * wv + (lane & 3)) * 32;

  const int hcol = gj * 64 + wv * 16 + l15;
  const int swzkey = (l15 & 7) << 4;                        // h_lds read key
  const char* abase = h_lds + l15 * 2048;
  const char* bbase = (const char*)w_lds + q * 1024 + (wv * 16 + l15) * 16;
  const float bias = bo[wv * 16 + l15];
  const char* wofb = (const char*)wof + ((q * 4 + wv) * 16 + l15) * 16;

  for (int t = 0; t < SEQ; ++t) {
    int xv = (lane < 16) ? x[(row0 + lane) * SEQ + t] : 0;
    // 1) recurrence MFMA: 16x16 tile (rows row0..+16 x wv col-slice), K=1024
    f32x4 a0 = {0.f, 0.f, 0.f, 0.f}, a1 = {0.f, 0.f, 0.f, 0.f};
    f32x4 a2 = {0.f, 0.f, 0.f, 0.f}, a3 = {0.f, 0.f, 0.f, 0.f};
    if (t > 0) {
      #pragma unroll 2
      for (int kb = 0; kb < 32; kb += 4) {
        short8 af0 = *(const short8*)(abase + (((kb + 0) * 64 + q * 16) ^ swzkey));
        short8 bf0 = *(const short8*)(bbase + (kb + 0) * 4096);
        a0 = __builtin_amdgcn_mfma_f32_16x16x32_bf16(af0, bf0, a0, 0, 0, 0);
        short8 af1 = *(const short8*)(abase + (((kb + 1) * 64 + q * 16) ^ swzkey));
        short8 bf1 = *(const short8*)(bbase + (kb + 1) * 4096);
        a1 = __builtin_amdgcn_mfma_f32_16x16x32_bf16(af1, bf1, a1, 0, 0, 0);
        short8 af2 = *(const short8*)(abase + (((kb + 2) * 64 + q * 16) ^ swzkey));
        short8 bf2 = *(const short8*)(bbase + (kb + 2) * 4096);
        a2 = __builtin_amdgcn_mfma_f32_16x16x32_bf16(af2, bf2, a2, 0, 0, 0);
        short8 af3 = *(const short8*)(abase + (((kb + 3) * 64 + q * 16) ^ swzkey));
        short8 bf3 = *(const short8*)(bbase + (kb + 3) * 4096);
        a3 = __builtin_amdgcn_mfma_f32_16x16x32_bf16(af3, bf3, a3, 0, 0, 0);
      }
    }
    // 2) epilogue: h_t = tanh(proj[x_t] + acc); publish packed col-pairs.
    unsigned short* slot = ring + (size_t)(t & (RING_SLOTS - 1)) * BH;
    float hv[4];
    #pragma unroll
    for (int r = 0; r < 4; ++r) {
      int row = q * 4 + r;                                  // D row
      int xi = __shfl(xv, row);
      float av = (a0[r] + a1[r]) + (a2[r] + a3[r]);
      hv[r] = ftanh(proj[(size_t)xi * HID + hcol] + av);
      if (t == SEQ - 1) final_out[(size_t)(row0 + row) * HID + hcol] = hv[r];
    }
    #pragma unroll
    for (int r = 0; r < 4; ++r) {
      unsigned myb = f2bf(hv[r]);
      unsigned oth = (unsigned)__shfl_xor((int)myb, 1);
      if ((l15 & 1) == 0) {
        int b = row0 + q * 4 + r;
        cstore32(slot + (size_t)b * HID + hcol, myb | (oth << 16));
      }
    }
    // 3) release: all-wave vmcnt(0) drain (r0-proven), then one flag store.
    __syncthreads();
    if (tid == 0) fstore(myflag, (unsigned)(t + 1));

    // 4) restage h_t for step t+1, wave-granular; logits overlapped inside.
    if (t < SEQ - 1) {
      // wave-local wait: our 4 producers at >= t+1. Only lanes 0..3 poll
      // (one lane per flag line); exponential backoff; bounded guard.
      {
        int g = 0;
        for (;;) {
          int cond = 1;
          if (lane < 4) cond = (fload(wflag) >= (unsigned)(t + 1));
          if (__all(cond)) break;
          backoff(g);
          if (++g > (1 << 14)) break;    // bailout: wrong answer beats a hang
        }
      }
      // issue restage loads (16 rows x 8B per thread, coalesced)
      u64 tmp[16];
      #pragma unroll
      for (int rr = 0; rr < 16; ++rr)
        tmp[rr] = cload64(slot + (size_t)(row0 + rr) * HID + tid * 4);
      // logits window (tsel <= t-2; visibility: step t-1's restage waits
      // established all 16 flags >= t, + syncthreads HB) — overlaps the
      // restage MALL RTT.
      if ((t & 15) == 1 && t >= 17) {
        int tsel = (t - 17) + gj;
        const unsigned short* hs =
            ring + (size_t)(tsel & (RING_SLOTS - 1)) * BH +
            (size_t)(row0 + l15) * HID + q * 8;             // A row base
        f32x4 lc = {0.f, 0.f, 0.f, 0.f};
        for (int g2 = 0; g2 < 4; ++g2) {
          u64 hb[16];
          #pragma unroll
          for (int j = 0; j < 8; ++j) {
            const unsigned short* pk = hs + (g2 * 8 + j) * 32;
            hb[2 * j]     = cload64(pk);
            hb[2 * j + 1] = cload64(pk + 4);
          }
          #pragma unroll
          for (int j = 0; j < 8; ++j) {
            union { u64 d[2]; short8 s8; } c;
            c.d[0] = hb[2 * j]; c.d[1] = hb[2 * j + 1];
            short8 w8 = *(const short8*)(wofb + (size_t)(g2 * 8 + j) * 4096);
            lc = __builtin_amdgcn_mfma_f32_16x16x32_bf16(c.s8, w8, lc, 0, 0, 0);
          }
        }
        #pragma unroll
        for (int rr = 0; rr < 4; ++rr) {
          int b = row0 + q * 4 + rr;
          out[((size_t)b * SEQ + tsel) * VOC + wv * 16 + l15] = lc[rr] + bias;
        }
        // reuse safe: tsel >= t-17 > t-32
      }
      // commit restage to LDS (XOR swizzle) and join waves
      #pragma unroll
      for (int rr = 0; rr < 16; ++rr)
        *(u64*)(h_lds + rr * 2048 + ((tid * 8) ^ ((rr & 7) << 4))) = tmp[rr];
      __syncthreads();
    }
  }

  // ---- final logits window: tsel = 496+gj, needs all 16 flags >= 512 ------
  {
    const unsigned* pf = flagg + (lane & 15) * 32;
    int g = 0;
    for (;;) {
      int cond = 1;
      if (lane < 16) cond = (fload(pf) >= (unsigned)SEQ);
      if (__all(cond)) break;
      backoff(g);
      if (++g > (1 << 14)) break;
    }
    int tsel = (SEQ - 16) + gj;
    const unsigned short* hs =
        ring + (size_t)(tsel & (RING_SLOTS - 1)) * BH +
        (size_t)(row0 + l15) * HID + q * 8;
    f32x4 lc = {0.f, 0.f, 0.f, 0.f};
    for (int g2 = 0; g2 < 4; ++g2) {
      u64 hb[16];
      #pragma unroll
      for (int j = 0; j < 8; ++j) {
        const unsigned short* pk = hs + (g2 * 8 + j) * 32;
        hb[2 * j]     = cload64(pk);
        hb[2 * j + 1] = cload64(pk + 4);
      }
      #pragma unroll
      for (int j = 0; j < 8; ++j) {
        union { u64 d[2]; short8 s8; } c;
        c.d[0] = hb[2 * j]; c.d[1] = hb[2 * j + 1];
        short8 w8 = *(const short8*)(wofb + (size_t)(g2 * 8 + j) * 4096);
        lc = __builtin_amdgcn_mfma_f32_16x16x32_bf16(c.s8, w8, lc, 0, 0, 0);
      }
    }
    #pragma unroll
    for (int rr = 0; rr < 4; ++rr) {
      int b = row0 + q * 4 + rr;
      out[((size_t)b * SEQ + tsel) * VOC + wv * 16 + l15] = lc[rr] + bias;
    }
  }
}

// ---------------- launch ----------------------------------------------------
extern "C" void kernel_launch(void* const* d_in, const int* in_sizes, int n_in,
                              void* d_out, int out_size, void* d_ws, size_t ws_size,
                              hipStream_t stream) {
  const int*   x   = (const int*)d_in[0];
  const float* emb = (const float*)d_in[1];
  const float* Wih = (const float*)d_in[2];
  const float* Whh = (const float*)d_in[3];
  const float* bh  = (const float*)d_in[4];
  const float* Who = (const float*)d_in[5];
  const float* bo  = (const float*)d_in[6];
  float* out = (float*)d_out;

  char* ws = (char*)d_ws;
  float*          proj  = (float*)ws;                        // 262144 B
  unsigned int*   flags = (unsigned int*)(ws + 262144);      // 32768 B
  unsigned short* wof   = (unsigned short*)(ws + 524288);    // 131072 B
  unsigned short* ring  = (unsigned short*)(ws + (1 << 20)); // 16 MiB

  size_t need = (size_t)(1 << 20) + (size_t)RING_SLOTS * BATCH * HID * 2;
  if (ws_size < need) return;  // diagnostic fail (absmax) instead of a fault

  (void)hipFuncSetAttribute(reinterpret_cast<const void*>(k_rnn),
                            hipFuncAttributeMaxDynamicSharedMemorySize, 163840);

  k_prep<<<256, 256, 0, stream>>>(emb, Wih, bh, proj);
  k_prep2<<<32, 256, 0, stream>>>(Who, wof);
  hipMemsetAsync(flags, 0, 32768, stream);
  k_rnn<<<256, 256, 163840, stream>>>(x, Whh, proj, wof, bo, ring,
                                      out, out + FINAL_OFF, flags);
}

// Round 12
// 2183.346 us; speedup vs baseline: 1.0980x; 1.0980x over previous
//
#include <hip/hip_runtime.h>
#include <stdint.h>

// CharRNN MI355X — r8 base (16 rows x 64 cols, counter barrier) + two edits:
//   (1) CHANNEL-SPREAD COUNTERS: group counters strided 8448B apart (was
//       128B). Theory: all prior sync schemes (r0/r4/r8/r11) co-located
//       their sync lines in a ~2KB span -> possible MALL-channel
//       serialization of 256 arrivals/step, a scheme-independent floor.
//       Zero op-count change; pure address-mapping test.
//   (2) LOGITS IN BARRIER WINDOW: barrier split arrive/wait; the every-16-
//       steps logits lump runs between them with tsel=(t-16)+gj <= t-1
//       (visibility: previous round's completion; slot hazard: t-tsel in
//       [1,16] < 32 ok). tsel=511 drained post-loop by gj==15 (barrier 512
//       already completed -> no extra wait). Takes ~3.6kcy off the chain on
//       logits steps.
//   Everything else byte-identical to r8 (current best, 2174us):
//   W_hh 1024x64 bf16 LDS B-frags, XOR-swizzled h_lds, ftanh, 4-chain accs,
//   packed col-pair publish, wof table, proj from global.
// d_ws: proj f32 @0 (256KB) | cnt @262144 (256KB region, counters 8448B
//       apart) | wof @524288 (128KB) | ring bf16 @1MB (16MB)

#define BATCH 256
#define SEQ   512
#define HID   1024
#define VOC   64
#define EMB   256
#define FINAL_OFF (BATCH * SEQ * VOC)   // 8388608
#define RING_SLOTS 32
#define BH (BATCH * HID)
#define CNT_STRIDE 8448                 // 8KB + 256B: cross-channel, no alias

typedef __attribute__((ext_vector_type(8))) short short8;
typedef __attribute__((ext_vector_type(4))) float f32x4;
typedef unsigned long long u64;

__device__ inline unsigned short f2bf(float f) {
  union { float f; unsigned u; } v; v.f = f;
  unsigned u = v.u;
  return (unsigned short)((u + 0x7FFFu + ((u >> 16) & 1u)) >> 16);  // RNE
}

// branch-free tanh: 1 - 2/(e^{2x}+1). Verified r7/r8 (absmax unchanged).
__device__ __forceinline__ float ftanh(float v) {
  float e = __expf(2.0f * v);
  return fmaf(-2.0f, __builtin_amdgcn_rcpf(e + 1.0f), 1.0f);
}

// ---- agent-scope (MALL-point) ops — the PROVEN coherence class -------------
__device__ inline u64 cload64(const unsigned short* p) {
  return __hip_atomic_load((const u64*)p, __ATOMIC_RELAXED,
                           __HIP_MEMORY_SCOPE_AGENT);
}
__device__ inline void cstore32(unsigned short* p, unsigned v) {
  __hip_atomic_store((unsigned*)p, v, __ATOMIC_RELAXED,
                     __HIP_MEMORY_SCOPE_AGENT);
}

// ---------------- K1: projection table -------------------------------------
__global__ __launch_bounds__(256) void k_prep(const float* __restrict__ emb,
                                              const float* __restrict__ Wih,
                                              const float* __restrict__ bh,
                                              float* __restrict__ proj) {
  __shared__ float es[EMB];
  const int v = blockIdx.x >> 2;        // 0..63
  const int p = blockIdx.x & 3;         // h-quarter
  const int tid = threadIdx.x;
  es[tid] = emb[v * EMB + tid];
  __syncthreads();
  const int h = p * 256 + tid;
  float acc = bh[h];
  for (int e = 0; e < EMB; ++e) acc += es[e] * Wih[e * HID + h];
  proj[v * HID + h] = acc;
}

// ---------------- K1b: W_ho bf16 fragment table (r6/r7/r8-proven) -----------
// entry e = ((kb*4+q)*4+vt)*16 + l15 ; elems j: Who[(kb*32+q*8+j)*VOC+vt*16+l15]
__global__ __launch_bounds__(256) void k_prep2(const float* __restrict__ Who,
                                               unsigned short* __restrict__ wof) {
  const int e = blockIdx.x * 256 + threadIdx.x;   // 0..8191
  const int l15 = e & 15, vt = (e >> 4) & 3, qq = (e >> 6) & 3, kb = e >> 8;
  #pragma unroll
  for (int j = 0; j < 8; ++j)
    wof[e * 8 + j] = f2bf(Who[(kb * 32 + qq * 8 + j) * VOC + vt * 16 + l15]);
}

// ---------------- split group barrier (r8 semantics, arrive/wait) -----------
__device__ __forceinline__ void barrier_arrive(unsigned int* cnt_i, int tid) {
  __syncthreads();                       // release: vmcnt(0) drain, all waves
  if (tid == 0) atomicAdd(cnt_i, 1u);
}
__device__ __forceinline__ void barrier_wait(unsigned int* cnt_i, int tid,
                                             int round) {
  if (tid == 0) {
    int guard = 0;
    while (__hip_atomic_load(cnt_i, __ATOMIC_RELAXED, __HIP_MEMORY_SCOPE_AGENT)
           < 16u * (unsigned)round) {
      __builtin_amdgcn_s_sleep(1);
      if (++guard > (1 << 16)) break;    // bailout: wrong answer beats a hang
    }
  }
  __syncthreads();                       // acquire broadcast
}

// ---------------- K2: persistent recurrence + inline logits ----------------
// LDS: w_lds 131072 (1024x64 bf16 B-frags) | h_lds 32768 (16 x 2048B, XOR swz)
__global__ __launch_bounds__(256, 1) void k_rnn(
    const int* __restrict__ x, const float* __restrict__ Whh,
    const float* __restrict__ proj, const unsigned short* __restrict__ wof,
    const float* __restrict__ bo, unsigned short* __restrict__ ring,
    float* __restrict__ out, float* __restrict__ final_out,
    unsigned int* __restrict__ cnt) {
  extern __shared__ char smem[];
  unsigned short* w_lds = (unsigned short*)smem;            // 131072
  char*           h_lds = smem + 131072;                    // 32768

  const int tid = threadIdx.x, bid = blockIdx.x;
  const int gi = bid & 15, gj = bid >> 4;   // group (16 rows) / col-slice (64)
  const int row0 = gi * 16;
  const int lane = tid & 63, wv = tid >> 6;                 // wv = nt slice
  const int l15 = lane & 15, q = lane >> 4;

  // W_hh column slice (1024 x 64) -> LDS bf16 B-fragment order (once).
  for (int it = 0; it < 256; ++it) {
    int u = it * 256 + tid;               // 0..65535
    int k = u >> 6, n = u & 63;           // coalesced over n
    int kb = k >> 5, qq = (k >> 3) & 3, j8 = k & 7;
    w_lds[(size_t)kb * 2048 + qq * 512 + n * 8 + j8] =
        f2bf(Whh[k * HID + gj * 64 + n]);
  }
  __syncthreads();

  // channel-spread counter: one per group, 8448B apart.
  unsigned int* cnt_i = (unsigned int*)((char*)cnt + gi * CNT_STRIDE);

  const int hcol = gj * 64 + wv * 16 + l15;
  const int swzkey = (l15 & 7) << 4;                        // h_lds read key
  const char* abase = h_lds + l15 * 2048;
  const char* bbase = (const char*)w_lds + q * 1024 + (wv * 16 + l15) * 16;
  const float bias = bo[wv * 16 + l15];
  const char* wofb = (const char*)wof + ((q * 4 + wv) * 16 + l15) * 16;

  for (int t = 0; t < SEQ; ++t) {
    int xv = (lane < 16) ? x[(row0 + lane) * SEQ + t] : 0;
    // 1) recurrence MFMA: 16x16 tile (rows row0..+16 x wv col-slice), K=1024
    f32x4 a0 = {0.f, 0.f, 0.f, 0.f}, a1 = {0.f, 0.f, 0.f, 0.f};
    f32x4 a2 = {0.f, 0.f, 0.f, 0.f}, a3 = {0.f, 0.f, 0.f, 0.f};
    if (t > 0) {
      #pragma unroll 2
      for (int kb = 0; kb < 32; kb += 4) {
        short8 af0 = *(const short8*)(abase + (((kb + 0) * 64 + q * 16) ^ swzkey));
        short8 bf0 = *(const short8*)(bbase + (kb + 0) * 4096);
        a0 = __builtin_amdgcn_mfma_f32_16x16x32_bf16(af0, bf0, a0, 0, 0, 0);
        short8 af1 = *(const short8*)(abase + (((kb + 1) * 64 + q * 16) ^ swzkey));
        short8 bf1 = *(const short8*)(bbase + (kb + 1) * 4096);
        a1 = __builtin_amdgcn_mfma_f32_16x16x32_bf16(af1, bf1, a1, 0, 0, 0);
        short8 af2 = *(const short8*)(abase + (((kb + 2) * 64 + q * 16) ^ swzkey));
        short8 bf2 = *(const short8*)(bbase + (kb + 2) * 4096);
        a2 = __builtin_amdgcn_mfma_f32_16x16x32_bf16(af2, bf2, a2, 0, 0, 0);
        short8 af3 = *(const short8*)(abase + (((kb + 3) * 64 + q * 16) ^ swzkey));
        short8 bf3 = *(const short8*)(bbase + (kb + 3) * 4096);
        a3 = __builtin_amdgcn_mfma_f32_16x16x32_bf16(af3, bf3, a3, 0, 0, 0);
      }
    }
    // 2) epilogue: h_t = tanh(proj[x_t] + acc); publish packed col-pairs.
    unsigned short* slot = ring + (size_t)(t & (RING_SLOTS - 1)) * BH;
    float hv[4];
    #pragma unroll
    for (int r = 0; r < 4; ++r) {
      int row = q * 4 + r;                                  // D row
      int xi = __shfl(xv, row);
      float av = (a0[r] + a1[r]) + (a2[r] + a3[r]);
      hv[r] = ftanh(proj[(size_t)xi * HID + hcol] + av);
      if (t == SEQ - 1) final_out[(size_t)(row0 + row) * HID + hcol] = hv[r];
    }
    #pragma unroll
    for (int r = 0; r < 4; ++r) {
      unsigned myb = f2bf(hv[r]);
      unsigned oth = (unsigned)__shfl_xor((int)myb, 1);
      if ((l15 & 1) == 0) {
        int b = row0 + q * 4 + r;
        cstore32(slot + (size_t)b * HID + hcol, myb | (oth << 16));
      }
    }
    // 3) barrier arrive (drain + atomicAdd), then independent work, then wait
    barrier_arrive(cnt_i, tid);
    // 4) logits lump in the barrier window: tsel <= t-1, proven visible by
    //    the PREVIOUS round's completion. Slot hazard: t - tsel in [1,16].
    if ((t & 15) == 15) {
      int tsel = (t - 16) + gj;
      if (tsel >= 0) {
        const unsigned short* hs =
            ring + (size_t)(tsel & (RING_SLOTS - 1)) * BH +
            (size_t)(row0 + l15) * HID + q * 8;             // A row base
        f32x4 lc = {0.f, 0.f, 0.f, 0.f};
        for (int g = 0; g < 4; ++g) {
          u64 hb[16];
          #pragma unroll
          for (int j = 0; j < 8; ++j) {
            const unsigned short* pk = hs + (g * 8 + j) * 32;
            hb[2 * j]     = cload64(pk);
            hb[2 * j + 1] = cload64(pk + 4);
          }
          #pragma unroll
          for (int j = 0; j < 8; ++j) {
            union { u64 d[2]; short8 s8; } c;
            c.d[0] = hb[2 * j]; c.d[1] = hb[2 * j + 1];
            short8 w8 = *(const short8*)(wofb + (size_t)(g * 8 + j) * 4096);
            lc = __builtin_amdgcn_mfma_f32_16x16x32_bf16(c.s8, w8, lc, 0, 0, 0);
          }
        }
        #pragma unroll
        for (int rr = 0; rr < 4; ++rr) {
          int b = row0 + q * 4 + rr;
          out[((size_t)b * SEQ + tsel) * VOC + wv * 16 + l15] = lc[rr] + bias;
        }
      }
    }
    barrier_wait(cnt_i, tid, t + 1);
    // 5) restage h_t (16 rows x 1024, coalesced agent loads) -> h_lds (XOR swz)
    if (t < SEQ - 1) {
      u64 tmp[16];
      #pragma unroll
      for (int rr = 0; rr < 16; ++rr)
        tmp[rr] = cload64(slot + (size_t)(row0 + rr) * HID + tid * 4);
      #pragma unroll
      for (int rr = 0; rr < 16; ++rr)
        *(u64*)(h_lds + rr * 2048 + ((tid * 8) ^ ((rr & 7) << 4))) = tmp[rr];
      __syncthreads();
    }
  }

  // ---- tail: tsel = 511 (only gj==15). Barrier round 512 completed, so
  //      slot 511 is globally visible; no extra wait needed.
  if (gj == 15) {
    int tsel = SEQ - 1;
    const unsigned short* hs =
        ring + (size_t)(tsel & (RING_SLOTS - 1)) * BH +
        (size_t)(row0 + l15) * HID + q * 8;
    f32x4 lc = {0.f, 0.f, 0.f, 0.f};
    for (int g = 0; g < 4; ++g) {
      u64 hb[16];
      #pragma unroll
      for (int j = 0; j < 8; ++j) {
        const unsigned short* pk = hs + (g * 8 + j) * 32;
        hb[2 * j]     = cload64(pk);
        hb[2 * j + 1] = cload64(pk + 4);
      }
      #pragma unroll
      for (int j = 0; j < 8; ++j) {
        union { u64 d[2]; short8 s8; } c;
        c.d[0] = hb[2 * j]; c.d[1] = hb[2 * j + 1];
        short8 w8 = *(const short8*)(wofb + (size_t)(g * 8 + j) * 4096);
        lc = __builtin_amdgcn_mfma_f32_16x16x32_bf16(c.s8, w8, lc, 0, 0, 0);
      }
    }
    #pragma unroll
    for (int rr = 0; rr < 4; ++rr) {
      int b = row0 + q * 4 + rr;
      out[((size_t)b * SEQ + tsel) * VOC + wv * 16 + l15] = lc[rr] + bias;
    }
  }
}

// ---------------- launch ----------------------------------------------------
extern "C" void kernel_launch(void* const* d_in, const int* in_sizes, int n_in,
                              void* d_out, int out_size, void* d_ws, size_t ws_size,
                              hipStream_t stream) {
  const int*   x   = (const int*)d_in[0];
  const float* emb = (const float*)d_in[1];
  const float* Wih = (const float*)d_in[2];
  const float* Whh = (const float*)d_in[3];
  const float* bh  = (const float*)d_in[4];
  const float* Who = (const float*)d_in[5];
  const float* bo  = (const float*)d_in[6];
  float* out = (float*)d_out;

  char* ws = (char*)d_ws;
  float*          proj = (float*)ws;                         // 262144 B
  unsigned int*   cnt  = (unsigned int*)(ws + 262144);       // 256KB region
  unsigned short* wof  = (unsigned short*)(ws + 524288);     // 131072 B
  unsigned short* ring = (unsigned short*)(ws + (1 << 20));  // 16 MiB

  size_t need = (size_t)(1 << 20) + (size_t)RING_SLOTS * BATCH * HID * 2;
  if (ws_size < need) return;  // diagnostic fail (absmax) instead of a fault

  (void)hipFuncSetAttribute(reinterpret_cast<const void*>(k_rnn),
                            hipFuncAttributeMaxDynamicSharedMemorySize, 163840);

  k_prep<<<256, 256, 0, stream>>>(emb, Wih, bh, proj);
  k_prep2<<<32, 256, 0, stream>>>(Who, wof);
  hipMemsetAsync(cnt, 0, 262144, stream);
  k_rnn<<<256, 256, 163840, stream>>>(x, Whh, proj, wof, bo, ring,
                                      out, out + FINAL_OFF, cnt);
}

// Round 13
// 1838.486 us; speedup vs baseline: 1.3039x; 1.1876x over previous
//
#include <hip/hip_runtime.h>
#include <stdint.h>

// CharRNN MI355X — r12 base + REGISTER-RESIDENT W_hh B-fragments.
//   r12 post-mortem: sync-side levers exhausted (all schemes ~2174-2270).
//   Execution-side decomposition: 4 waves x 64 ds_read_b128 = 256KB LDS
//   reads/CU/step ~3kcy = biggest identifiable chunk; plus ~520cy/step of
//   bank conflicts (r8's XOR swizzle still ~8-way on A-reads).
//   This round:
//     - W_hh is step-invariant and occupancy is 1 wave/SIMD -> each wave
//       loads its 32 B-frags into registers ONCE (128 VGPR; r5's spill was
//       256 VGPR for 2 col-slices). Halves per-step LDS reads; kills B-read
//       conflicts.
//     - w_lds (128KB) freed -> h_lds moves there with stride 2064 (r0's
//       padded layout: row*2064 mod 128 = row*16 -> each 8-lane group
//       covers all 32 banks -> conflict-free A-reads, no XOR swizzle).
//   Everything else byte-identical to r12 (16x64 geometry, split counter
//   barrier w/ logits in the window, ftanh, 4-chain accs, packed publish,
//   wof table, proj from global).
// d_ws: proj f32 @0 (256KB) | cnt @262144 (256KB, 8448B stride) |
//       wof @524288 (128KB) | ring bf16 @1MB (16MB)

#define BATCH 256
#define SEQ   512
#define HID   1024
#define VOC   64
#define EMB   256
#define FINAL_OFF (BATCH * SEQ * VOC)   // 8388608
#define RING_SLOTS 32
#define BH (BATCH * HID)
#define CNT_STRIDE 8448

typedef __attribute__((ext_vector_type(8))) short short8;
typedef __attribute__((ext_vector_type(4))) float f32x4;
typedef unsigned long long u64;

__device__ inline unsigned short f2bf(float f) {
  union { float f; unsigned u; } v; v.f = f;
  unsigned u = v.u;
  return (unsigned short)((u + 0x7FFFu + ((u >> 16) & 1u)) >> 16);  // RNE
}

// branch-free tanh: 1 - 2/(e^{2x}+1). Verified r7/r8/r12 (absmax unchanged).
__device__ __forceinline__ float ftanh(float v) {
  float e = __expf(2.0f * v);
  return fmaf(-2.0f, __builtin_amdgcn_rcpf(e + 1.0f), 1.0f);
}

// ---- agent-scope (MALL-point) ops — the PROVEN coherence class -------------
__device__ inline u64 cload64(const unsigned short* p) {
  return __hip_atomic_load((const u64*)p, __ATOMIC_RELAXED,
                           __HIP_MEMORY_SCOPE_AGENT);
}
__device__ inline void cstore32(unsigned short* p, unsigned v) {
  __hip_atomic_store((unsigned*)p, v, __ATOMIC_RELAXED,
                     __HIP_MEMORY_SCOPE_AGENT);
}

// ---------------- K1: projection table -------------------------------------
__global__ __launch_bounds__(256) void k_prep(const float* __restrict__ emb,
                                              const float* __restrict__ Wih,
                                              const float* __restrict__ bh,
                                              float* __restrict__ proj) {
  __shared__ float es[EMB];
  const int v = blockIdx.x >> 2;        // 0..63
  const int p = blockIdx.x & 3;         // h-quarter
  const int tid = threadIdx.x;
  es[tid] = emb[v * EMB + tid];
  __syncthreads();
  const int h = p * 256 + tid;
  float acc = bh[h];
  for (int e = 0; e < EMB; ++e) acc += es[e] * Wih[e * HID + h];
  proj[v * HID + h] = acc;
}

// ---------------- K1b: W_ho bf16 fragment table (r6/r7/r8-proven) -----------
// entry e = ((kb*4+q)*4+vt)*16 + l15 ; elems j: Who[(kb*32+q*8+j)*VOC+vt*16+l15]
__global__ __launch_bounds__(256) void k_prep2(const float* __restrict__ Who,
                                               unsigned short* __restrict__ wof) {
  const int e = blockIdx.x * 256 + threadIdx.x;   // 0..8191
  const int l15 = e & 15, vt = (e >> 4) & 3, qq = (e >> 6) & 3, kb = e >> 8;
  #pragma unroll
  for (int j = 0; j < 8; ++j)
    wof[e * 8 + j] = f2bf(Who[(kb * 32 + qq * 8 + j) * VOC + vt * 16 + l15]);
}

// ---------------- split group barrier (r12) ---------------------------------
__device__ __forceinline__ void barrier_arrive(unsigned int* cnt_i, int tid) {
  __syncthreads();                       // release: vmcnt(0) drain, all waves
  if (tid == 0) atomicAdd(cnt_i, 1u);
}
__device__ __forceinline__ void barrier_wait(unsigned int* cnt_i, int tid,
                                             int round) {
  if (tid == 0) {
    int guard = 0;
    while (__hip_atomic_load(cnt_i, __ATOMIC_RELAXED, __HIP_MEMORY_SCOPE_AGENT)
           < 16u * (unsigned)round) {
      __builtin_amdgcn_s_sleep(1);
      if (++guard > (1 << 16)) break;    // bailout: wrong answer beats a hang
    }
  }
  __syncthreads();                       // acquire broadcast
}

// ---------------- K2: persistent recurrence + inline logits ----------------
// LDS 131072: used first as W_hh B-frag staging (128KB), then REUSED as
// h_lds (16 rows x 2064B = 33024B, padded stride -> conflict-free A-reads).
__global__ __launch_bounds__(256, 1) void k_rnn(
    const int* __restrict__ x, const float* __restrict__ Whh,
    const float* __restrict__ proj, const unsigned short* __restrict__ wof,
    const float* __restrict__ bo, unsigned short* __restrict__ ring,
    float* __restrict__ out, float* __restrict__ final_out,
    unsigned int* __restrict__ cnt) {
  extern __shared__ char smem[];
  unsigned short* w_lds = (unsigned short*)smem;            // staging (dies)
  char*           h_lds = smem;                             // reuses region

  const int tid = threadIdx.x, bid = blockIdx.x;
  const int gi = bid & 15, gj = bid >> 4;   // group (16 rows) / col-slice (64)
  const int row0 = gi * 16;
  const int lane = tid & 63, wv = tid >> 6;                 // wv = nt slice
  const int l15 = lane & 15, q = lane >> 4;

  // W_hh column slice (1024 x 64) -> LDS bf16 B-fragment order (staging).
  for (int it = 0; it < 256; ++it) {
    int u = it * 256 + tid;               // 0..65535
    int k = u >> 6, n = u & 63;           // coalesced over n
    int kb = k >> 5, qq = (k >> 3) & 3, j8 = k & 7;
    w_lds[(size_t)kb * 2048 + qq * 512 + n * 8 + j8] =
        f2bf(Whh[k * HID + gj * 64 + n]);
  }
  __syncthreads();

  // B-fragments -> REGISTERS (once; W_hh is step-invariant). 128 VGPR.
  short8 bfr[32];
  {
    const char* bbase = (const char*)w_lds + q * 1024 + (wv * 16 + l15) * 16;
    #pragma unroll
    for (int kb = 0; kb < 32; ++kb)
      bfr[kb] = *(const short8*)(bbase + (size_t)kb * 4096);
  }
  __syncthreads();                        // staging dead; region becomes h_lds

  unsigned int* cnt_i = (unsigned int*)((char*)cnt + gi * CNT_STRIDE);

  const int hcol = gj * 64 + wv * 16 + l15;
  const char* abase = h_lds + l15 * 2064 + q * 16;  // stride 2064: bank-clean
  const float bias = bo[wv * 16 + l15];
  const char* wofb = (const char*)wof + ((q * 4 + wv) * 16 + l15) * 16;

  for (int t = 0; t < SEQ; ++t) {
    int xv = (lane < 16) ? x[(row0 + lane) * SEQ + t] : 0;
    // 1) recurrence MFMA: 16x16 tile, K=1024; A from LDS, B from registers.
    f32x4 a0 = {0.f, 0.f, 0.f, 0.f}, a1 = {0.f, 0.f, 0.f, 0.f};
    f32x4 a2 = {0.f, 0.f, 0.f, 0.f}, a3 = {0.f, 0.f, 0.f, 0.f};
    if (t > 0) {
      #pragma unroll
      for (int kb = 0; kb < 32; kb += 4) {
        short8 af0 = *(const short8*)(abase + (kb + 0) * 64);
        a0 = __builtin_amdgcn_mfma_f32_16x16x32_bf16(af0, bfr[kb + 0], a0, 0, 0, 0);
        short8 af1 = *(const short8*)(abase + (kb + 1) * 64);
        a1 = __builtin_amdgcn_mfma_f32_16x16x32_bf16(af1, bfr[kb + 1], a1, 0, 0, 0);
        short8 af2 = *(const short8*)(abase + (kb + 2) * 64);
        a2 = __builtin_amdgcn_mfma_f32_16x16x32_bf16(af2, bfr[kb + 2], a2, 0, 0, 0);
        short8 af3 = *(const short8*)(abase + (kb + 3) * 64);
        a3 = __builtin_amdgcn_mfma_f32_16x16x32_bf16(af3, bfr[kb + 3], a3, 0, 0, 0);
      }
    }
    // 2) epilogue: h_t = tanh(proj[x_t] + acc); publish packed col-pairs.
    unsigned short* slot = ring + (size_t)(t & (RING_SLOTS - 1)) * BH;
    float hv[4];
    #pragma unroll
    for (int r = 0; r < 4; ++r) {
      int row = q * 4 + r;                                  // D row
      int xi = __shfl(xv, row);
      float av = (a0[r] + a1[r]) + (a2[r] + a3[r]);
      hv[r] = ftanh(proj[(size_t)xi * HID + hcol] + av);
      if (t == SEQ - 1) final_out[(size_t)(row0 + row) * HID + hcol] = hv[r];
    }
    #pragma unroll
    for (int r = 0; r < 4; ++r) {
      unsigned myb = f2bf(hv[r]);
      unsigned oth = (unsigned)__shfl_xor((int)myb, 1);
      if ((l15 & 1) == 0) {
        int b = row0 + q * 4 + r;
        cstore32(slot + (size_t)b * HID + hcol, myb | (oth << 16));
      }
    }
    // 3) barrier arrive (drain + atomicAdd), then independent work, then wait
    barrier_arrive(cnt_i, tid);
    // 4) logits lump in the barrier window: tsel <= t-1 (proven visible by
    //    the PREVIOUS round's completion). Slot hazard: t - tsel in [1,16].
    if ((t & 15) == 15) {
      int tsel = (t - 16) + gj;
      if (tsel >= 0) {
        const unsigned short* hs =
            ring + (size_t)(tsel & (RING_SLOTS - 1)) * BH +
            (size_t)(row0 + l15) * HID + q * 8;             // A row base
        f32x4 lc = {0.f, 0.f, 0.f, 0.f};
        for (int g = 0; g < 4; ++g) {
          u64 hb[16];
          #pragma unroll
          for (int j = 0; j < 8; ++j) {
            const unsigned short* pk = hs + (g * 8 + j) * 32;
            hb[2 * j]     = cload64(pk);
            hb[2 * j + 1] = cload64(pk + 4);
          }
          #pragma unroll
          for (int j = 0; j < 8; ++j) {
            union { u64 d[2]; short8 s8; } c;
            c.d[0] = hb[2 * j]; c.d[1] = hb[2 * j + 1];
            short8 w8 = *(const short8*)(wofb + (size_t)(g * 8 + j) * 4096);
            lc = __builtin_amdgcn_mfma_f32_16x16x32_bf16(c.s8, w8, lc, 0, 0, 0);
          }
        }
        #pragma unroll
        for (int rr = 0; rr < 4; ++rr) {
          int b = row0 + q * 4 + rr;
          out[((size_t)b * SEQ + tsel) * VOC + wv * 16 + l15] = lc[rr] + bias;
        }
      }
    }
    barrier_wait(cnt_i, tid, t + 1);
    // 5) restage h_t (16 rows x 1024, coalesced agent loads) -> h_lds (2064)
    if (t < SEQ - 1) {
      u64 tmp[16];
      #pragma unroll
      for (int rr = 0; rr < 16; ++rr)
        tmp[rr] = cload64(slot + (size_t)(row0 + rr) * HID + tid * 4);
      #pragma unroll
      for (int rr = 0; rr < 16; ++rr)
        *(u64*)(h_lds + rr * 2064 + tid * 8) = tmp[rr];
      __syncthreads();
    }
  }

  // ---- tail: tsel = 511 (only gj==15). Barrier round 512 completed, so
  //      slot 511 is globally visible; no extra wait needed.
  if (gj == 15) {
    int tsel = SEQ - 1;
    const unsigned short* hs =
        ring + (size_t)(tsel & (RING_SLOTS - 1)) * BH +
        (size_t)(row0 + l15) * HID + q * 8;
    f32x4 lc = {0.f, 0.f, 0.f, 0.f};
    for (int g = 0; g < 4; ++g) {
      u64 hb[16];
      #pragma unroll
      for (int j = 0; j < 8; ++j) {
        const unsigned short* pk = hs + (g * 8 + j) * 32;
        hb[2 * j]     = cload64(pk);
        hb[2 * j + 1] = cload64(pk + 4);
      }
      #pragma unroll
      for (int j = 0; j < 8; ++j) {
        union { u64 d[2]; short8 s8; } c;
        c.d[0] = hb[2 * j]; c.d[1] = hb[2 * j + 1];
        short8 w8 = *(const short8*)(wofb + (size_t)(g * 8 + j) * 4096);
        lc = __builtin_amdgcn_mfma_f32_16x16x32_bf16(c.s8, w8, lc, 0, 0, 0);
      }
    }
    #pragma unroll
    for (int rr = 0; rr < 4; ++rr) {
      int b = row0 + q * 4 + rr;
      out[((size_t)b * SEQ + tsel) * VOC + wv * 16 + l15] = lc[rr] + bias;
    }
  }
}

// ---------------- launch ----------------------------------------------------
extern "C" void kernel_launch(void* const* d_in, const int* in_sizes, int n_in,
                              void* d_out, int out_size, void* d_ws, size_t ws_size,
                              hipStream_t stream) {
  const int*   x   = (const int*)d_in[0];
  const float* emb = (const float*)d_in[1];
  const float* Wih = (const float*)d_in[2];
  const float* Whh = (const float*)d_in[3];
  const float* bh  = (const float*)d_in[4];
  const float* Who = (const float*)d_in[5];
  const float* bo  = (const float*)d_in[6];
  float* out = (float*)d_out;

  char* ws = (char*)d_ws;
  float*          proj = (float*)ws;                         // 262144 B
  unsigned int*   cnt  = (unsigned int*)(ws + 262144);       // 256KB region
  unsigned short* wof  = (unsigned short*)(ws + 524288);     // 131072 B
  unsigned short* ring = (unsigned short*)(ws + (1 << 20));  // 16 MiB

  size_t need = (size_t)(1 << 20) + (size_t)RING_SLOTS * BATCH * HID * 2;
  if (ws_size < need) return;  // diagnostic fail (absmax) instead of a fault

  (void)hipFuncSetAttribute(reinterpret_cast<const void*>(k_rnn),
                            hipFuncAttributeMaxDynamicSharedMemorySize, 131072);

  k_prep<<<256, 256, 0, stream>>>(emb, Wih, bh, proj);
  k_prep2<<<32, 256, 0, stream>>>(Who, wof);
  hipMemsetAsync(cnt, 0, 262144, stream);
  k_rnn<<<256, 256, 131072, stream>>>(x, Whh, proj, wof, bo, ring,
                                      out, out + FINAL_OFF, cnt);
}